// Round 6
// baseline (184.349 us; speedup 1.0000x reference)
//
#include <hip/hip_runtime.h>

// MSE_DQ_FK: dual-quaternion denorm -> local rot -> FK -> mse losses -> scalar.
// B=64, T=1024, J=22, C=176. Layout (B,C,T), T contiguous. Only rotation
// quats (4 of 8 dq channels) are read. Telescoping identity: global rot[j] =
// conj(q0n)*qjn; ik/dec roots are identity.
//
// Round-8 structure: FLOAT2 POSE-PAIR + ROLE SPLIT + DEPTH-1 SW PIPELINE.
//   Cross-round per-CU load-instr efficiency: R3 (many waves) 30 ns/instr,
//   R0 (pipelined prefetch) 37, R4 42, R5 (single-buffered float2) 66.
//   R5 won on instruction COUNT (688/CU, half of R4) but lost efficiency by
//   dropping the prefetch pipeline: each batch's loads were consumed
//   immediately -> full L3/L2 latency exposed per batch at 1 wave/SIMD.
//   Fix: 3-joint double-buffered batches; issue batch k+1 (24 dwordx2),
//   compute batch k (3 joints x 2 poses ~ 1000+ VALU cycles > L3 latency).
//   Batches: [1-3][4-6][7-9][10-12][13-15][16-18][19-21].
//     role 0 (blocks 0-127):   {ik, tgt} -> EE losses (joints 4,8,13,17,21)
//     role 1 (blocks 128-255): {dec, ik} -> REG losses (16 non-sparse)
//   Register budget: 2 buffers x 24 F2 = 96 + FK state 56 + branch save 28
//   + q0c/accum/temps ~= 210 < 256 (no launch_bounds cap; R1/R2/R4 showed
//   forcing min-waves pins 128 VGPR -> 44MB spill).
//  * UNIT-QUAT FROBENIUS IDENTITY: ||R(a)-R(b)||_F^2 = 8*(1 - dot(a,b)^2).

#define T_DIM 1024

struct alignas(8) F2 { float u, v; };

__device__ __forceinline__ F2 operator+(F2 a, F2 b){ return {a.u+b.u, a.v+b.v}; }
__device__ __forceinline__ F2 operator-(F2 a, F2 b){ return {a.u-b.u, a.v-b.v}; }
__device__ __forceinline__ F2 operator*(F2 a, F2 b){ return {a.u*b.u, a.v*b.v}; }
__device__ __forceinline__ F2 operator*(F2 a, float s){ return {a.u*s, a.v*s}; }
__device__ __forceinline__ F2 operator+(F2 a, float s){ return {a.u+s, a.v+s}; }
__device__ __forceinline__ F2 f2neg(F2 a){ return {-a.u, -a.v}; }
__device__ __forceinline__ F2 f2bc(float s){ return {s, s}; }
__device__ __forceinline__ F2 f2rsq(F2 a){ return {rsqrtf(a.u), rsqrtf(a.v)}; }

struct Q2 { F2 w, x, y, z; };
struct V2 { F2 x, y, z; };
struct St2 { Q2 rot; V2 pos; };

__device__ __forceinline__ Q2 qmul2(const Q2 a, const Q2 b) {
    Q2 r;
    r.w = a.w*b.w - a.x*b.x - a.y*b.y - a.z*b.z;
    r.x = a.w*b.x + a.x*b.w + a.y*b.z - a.z*b.y;
    r.y = a.w*b.y - a.x*b.z + a.y*b.w + a.z*b.x;
    r.z = a.w*b.z + a.x*b.y - a.y*b.x + a.z*b.w;
    return r;
}

// rotate the CONSTANT offset vector (ox,oy,oz) by quat pair q
__device__ __forceinline__ V2 qrot2(const Q2 q, float ox, float oy, float oz) {
    F2 tx = (q.y*oz - q.z*oy)*2.f;
    F2 ty = (q.z*ox - q.x*oz)*2.f;
    F2 tz = (q.x*oy - q.y*ox)*2.f;
    V2 r;
    r.x = (q.w*tx + (q.y*tz - q.z*ty)) + ox;
    r.y = (q.w*ty + (q.z*tx - q.x*tz)) + oy;
    r.z = (q.w*tz + (q.x*ty - q.y*tx)) + oz;
    return r;
}

// ||R(a)-R(b)||_F^2 for UNIT quats = 8*(1 - dot(a,b)^2)
__device__ __forceinline__ F2 rmdiff2u(const Q2 a, const Q2 b) {
    F2 d = a.w*b.w + a.x*b.x + a.y*b.y + a.z*b.z;
    return (f2bc(1.f) - d*d)*8.f;
}

__device__ __forceinline__ F2 pdiff2(const V2 a, const V2 b) {
    F2 dx = a.x-b.x, dy = a.y-b.y, dz = a.z-b.z;
    return dx*dx + dy*dy + dz*dz;
}

// Denorm raw quat channels then normalize. c0 is a literal after unroll ->
// mean/stdv become scalar loads.
__device__ __forceinline__ Q2 mkq2(const F2 r[4], const int c0,
                                   const float* __restrict__ mean,
                                   const float* __restrict__ stdv) {
    Q2 q;
    q.w = r[0]*stdv[c0+0] + mean[c0+0];
    q.x = r[1]*stdv[c0+1] + mean[c0+1];
    q.y = r[2]*stdv[c0+2] + mean[c0+2];
    q.z = r[3]*stdv[c0+3] + mean[c0+3];
    F2 inv = f2rsq(q.w*q.w + q.x*q.x + q.y*q.y + q.z*q.z);
    q.w = q.w*inv; q.x = q.x*inv; q.y = q.y*inv; q.z = q.z*inv;
    return q;
}

// float2 load at uniform base + (literal channel + per-thread t0) offset.
__device__ __forceinline__ F2 ld2(const float* __restrict__ base, int idx) {
    return *reinterpret_cast<const F2*>(base + idx);
}

// Load raw quat channels for joints J0..J0+2, both streams, pose pair.
// ik base is pre-shifted by -8*T_DIM (its array lacks the root joint).
template<int J0>
__device__ __forceinline__ void ldb3(
    const float* __restrict__ xp, const float* __restrict__ yp, const int t0,
    F2 (*X)[4], F2 (*Y)[4])
{
#pragma unroll
    for (int jj = 0; jj < 3; ++jj) {
#pragma unroll
        for (int c = 0; c < 4; ++c) {
            X[jj][c] = ld2(xp, ((J0+jj)*8 + c)*T_DIM + t0);
            Y[jj][c] = ld2(yp, ((J0+jj)*8 + c)*T_DIM + t0);
        }
    }
}

// One joint step for both streams, pose pair.
template<int J, bool LOSS, bool PRE>
__device__ __forceinline__ void stepf(
    St2& sx, St2& sy,
    const F2 xr[4], const F2 yr[4],
    const float* __restrict__ mean, const float* __restrict__ stdv,
    const float* __restrict__ offs, const Q2& q0c,
    F2& ap, F2& ar)
{
    const int c0 = J*8;
    Q2 qx = mkq2(xr, c0, mean, stdv);
    Q2 qy = mkq2(yr, c0, mean, stdv);
    if (PRE) qy = qmul2(q0c, qy);
    const float ox = offs[3*J], oy = offs[3*J+1], oz = offs[3*J+2];
    V2 dx = qrot2(sx.rot, ox, oy, oz);
    V2 dy = qrot2(sy.rot, ox, oy, oz);
    V2 px = { dx.x + sx.pos.x, dx.y + sx.pos.y, dx.z + sx.pos.z };
    V2 py = { dy.x + sy.pos.x, dy.y + sy.pos.y, dy.z + sy.pos.z };
    if (LOSS) {
        ap = ap + pdiff2(px, py);
        ar = ar + rmdiff2u(qx, qy);
    }
    sx.rot = qx; sx.pos = px;
    sy.rot = qy; sy.pos = py;
}

// Walk all 21 joints with a depth-1 software pipeline over 3-joint batches.
// Double buffers A/B: issue the next batch's 24 dwordx2 loads, then compute
// the current batch (3 joints x 2 poses of VALU covers the load latency).
// EEROLE=true : X=ik, Y=tgt (root premult), loss at EE joints {4,8,13,17,21}
// EEROLE=false: X=dec, Y=ik, loss at the 16 non-sparse joints
template<bool EEROLE>
__device__ __forceinline__ void walk(
    const float* __restrict__ xp, const float* __restrict__ yp, const int t0,
    const float* __restrict__ mean, const float* __restrict__ stdv,
    const float* __restrict__ offs, F2& ap, F2& ar)
{
    // PARENTS = [0,0,1,2,3, 0,5,6,7, 0,9,10,11,12, 11,14,15,16, 11,18,19,20]
    // Chains: A=1..4(EE4) B=5..8(EE8) C=9..13(EE13,branch@11) D=14..17(EE17)
    //         E=18..21(EE21)
    F2 Ax[3][4], Ay[3][4], Bx[3][4], By[3][4];
    F2 rq0[4];

    // prologue: root (EE only) + first two batches in flight
    if (EEROLE) {
#pragma unroll
        for (int c = 0; c < 4; ++c) rq0[c] = ld2(yp, c*T_DIM + t0);
    }
    ldb3<1>(xp, yp, t0, Ax, Ay);     // joints 1,2,3
    ldb3<4>(xp, yp, t0, Bx, By);     // joints 4,5,6

    Q2 q0c = { f2bc(1.f), f2bc(0.f), f2bc(0.f), f2bc(0.f) };
    if (EEROLE) {
        Q2 q0 = mkq2(rq0, 0, mean, stdv);
        q0c = { q0.w, f2neg(q0.x), f2neg(q0.y), f2neg(q0.z) };
    }
    const St2 root = { { f2bc(1.f), f2bc(0.f), f2bc(0.f), f2bc(0.f) },
                       { f2bc(0.f), f2bc(0.f), f2bc(0.f) } };
    St2 sx = root, sy = root;
    St2 sx11, sy11;

    // batch 1: joints 1,2,3 (chain A interior)
    stepf<1, !EEROLE, EEROLE>(sx,sy, Ax[0],Ay[0], mean,stdv,offs,q0c, ap,ar);
    stepf<2, !EEROLE, EEROLE>(sx,sy, Ax[1],Ay[1], mean,stdv,offs,q0c, ap,ar);
    stepf<3, !EEROLE, EEROLE>(sx,sy, Ax[2],Ay[2], mean,stdv,offs,q0c, ap,ar);
    ldb3<7>(xp, yp, t0, Ax, Ay);     // joints 7,8,9

    // batch 2: joint 4 (EE of chain A), then 5,6 (chain B starts at root)
    stepf<4,  EEROLE, EEROLE>(sx,sy, Bx[0],By[0], mean,stdv,offs,q0c, ap,ar);
    sx = root; sy = root;
    stepf<5, !EEROLE, EEROLE>(sx,sy, Bx[1],By[1], mean,stdv,offs,q0c, ap,ar);
    stepf<6, !EEROLE, EEROLE>(sx,sy, Bx[2],By[2], mean,stdv,offs,q0c, ap,ar);
    ldb3<10>(xp, yp, t0, Bx, By);    // joints 10,11,12

    // batch 3: joints 7, 8 (EE of chain B), then 9 (chain C starts at root)
    stepf<7, !EEROLE, EEROLE>(sx,sy, Ax[0],Ay[0], mean,stdv,offs,q0c, ap,ar);
    stepf<8,  EEROLE, EEROLE>(sx,sy, Ax[1],Ay[1], mean,stdv,offs,q0c, ap,ar);
    sx = root; sy = root;
    stepf<9, !EEROLE, EEROLE>(sx,sy, Ax[2],Ay[2], mean,stdv,offs,q0c, ap,ar);
    ldb3<13>(xp, yp, t0, Ax, Ay);    // joints 13,14,15

    // batch 4: joints 10, 11 (branch point: save), 12
    stepf<10, !EEROLE, EEROLE>(sx,sy, Bx[0],By[0], mean,stdv,offs,q0c, ap,ar);
    stepf<11, !EEROLE, EEROLE>(sx,sy, Bx[1],By[1], mean,stdv,offs,q0c, ap,ar);
    sx11 = sx; sy11 = sy;
    stepf<12, !EEROLE, EEROLE>(sx,sy, Bx[2],By[2], mean,stdv,offs,q0c, ap,ar);
    ldb3<16>(xp, yp, t0, Bx, By);    // joints 16,17,18

    // batch 5: joint 13 (EE of chain C), then 14,15 (chain D from branch)
    stepf<13,  EEROLE, EEROLE>(sx,sy, Ax[0],Ay[0], mean,stdv,offs,q0c, ap,ar);
    sx = sx11; sy = sy11;
    stepf<14, !EEROLE, EEROLE>(sx,sy, Ax[1],Ay[1], mean,stdv,offs,q0c, ap,ar);
    stepf<15, !EEROLE, EEROLE>(sx,sy, Ax[2],Ay[2], mean,stdv,offs,q0c, ap,ar);
    ldb3<19>(xp, yp, t0, Ax, Ay);    // joints 19,20,21

    // batch 6: joints 16, 17 (EE of chain D), then 18 (chain E from branch)
    stepf<16, !EEROLE, EEROLE>(sx,sy, Bx[0],By[0], mean,stdv,offs,q0c, ap,ar);
    stepf<17,  EEROLE, EEROLE>(sx,sy, Bx[1],By[1], mean,stdv,offs,q0c, ap,ar);
    sx = sx11; sy = sy11;
    stepf<18, !EEROLE, EEROLE>(sx,sy, Bx[2],By[2], mean,stdv,offs,q0c, ap,ar);

    // batch 7: joints 19, 20, 21 (EE of chain E)
    stepf<19, !EEROLE, EEROLE>(sx,sy, Ax[0],Ay[0], mean,stdv,offs,q0c, ap,ar);
    stepf<20, !EEROLE, EEROLE>(sx,sy, Ax[1],Ay[1], mean,stdv,offs,q0c, ap,ar);
    stepf<21,  EEROLE, EEROLE>(sx,sy, Ax[2],Ay[2], mean,stdv,offs,q0c, ap,ar);
}

__global__ __launch_bounds__(256) void fk_loss_kernel(
    const float* __restrict__ ik, const float* __restrict__ dec,
    const float* __restrict__ tgt, const float* __restrict__ mean,
    const float* __restrict__ stdv, const float* __restrict__ offs,
    float* __restrict__ out)
{
    __shared__ float swred[4];
    const int tid = threadIdx.x;
    const int bid = blockIdx.x;
    // 128 pose-blocks x 2 roles = 256 blocks. bid and bid+128 are congruent
    // mod 8 -> same XCD -> role 1's ik re-read hits that XCD's L2.
    const int role = bid >> 7;
    const int pb   = bid & 127;          // pose block: 512 poses
    const int bb   = pb >> 1;            // batch index b (BLOCK-UNIFORM)
    const int t0   = (pb & 1)*512 + 2*tid;   // even; pose pair (t0, t0+1)

    // bases are blockIdx-derived only -> wave-uniform -> SGPR base +
    // per-thread VGPR offset addressing.
    // ik base pre-shifted by -8*T_DIM (array lacks root joint; j>=1 always).
    const float* ikp = ik  + (size_t)bb * (168*1024) - (size_t)(8*T_DIM);
    const float* dep = dec + (size_t)bb * (176*1024);
    const float* tgp = tgt + (size_t)bb * (176*1024);

    F2 ap = f2bc(0.f), ar = f2bc(0.f);
    float loss;
    const float BT = 65536.f;
    if (role == 0) {
        // loss_ee = ee_pos/(B*T*5*3) + ee_rm/(B*T*5*9)
        walk<true>(ikp, tgp, t0, mean, stdv, offs, ap, ar);
        loss = (ap.u + ap.v) * (1.0f/(BT*15.f))
             + (ar.u + ar.v) * (1.0f/(BT*45.f));
    } else {
        // loss_reg = 0.1*( reg_pos/(B*T*16*3) + reg_rm/(B*T*16*9) )
        walk<false>(dep, ikp, t0, mean, stdv, offs, ap, ar);
        loss = (ap.u + ap.v) * (0.1f/(BT*48.f))
             + (ar.u + ar.v) * (0.1f/(BT*144.f));
    }

    // wave(64) shuffle reduce -> cross-wave via LDS -> one atomic per block
#pragma unroll
    for (int o = 32; o > 0; o >>= 1) loss += __shfl_down(loss, o);
    if ((tid & 63) == 0) swred[tid >> 6] = loss;
    __syncthreads();
    if (tid == 0) {
        atomicAdd(out, swred[0]+swred[1]+swred[2]+swred[3]);
    }
}

extern "C" void kernel_launch(void* const* d_in, const int* in_sizes, int n_in,
                              void* d_out, int out_size, void* d_ws, size_t ws_size,
                              hipStream_t stream) {
    // inputs (setup_inputs order): input(unused), input_ik, input_decoder,
    // target, mean_dqs, std_dqs, offsets
    const float* ikx  = (const float*)d_in[1];
    const float* dec  = (const float*)d_in[2];
    const float* tgt  = (const float*)d_in[3];
    const float* mean = (const float*)d_in[4];
    const float* stdv = (const float*)d_in[5];
    const float* offs = (const float*)d_in[6];
    float* out = (float*)d_out;

    hipMemsetAsync(out, 0, sizeof(float), stream);
    // 128 pose-blocks x 2 roles = 256 blocks of 256 threads (1 block/CU);
    // each thread carries a pose pair via float2 loads.
    fk_loss_kernel<<<256, 256, 0, stream>>>(ikx, dec, tgt, mean, stdv, offs, out);
}